// Round 3
// baseline (755.747 us; speedup 1.0000x reference)
//
#include <hip/hip_runtime.h>

#define DEV __device__ __forceinline__

typedef __attribute__((ext_vector_type(8))) short bf16x8;
typedef __attribute__((ext_vector_type(4))) float f32x4;

typedef const __attribute__((address_space(1))) void* gsrc_t;
typedef __attribute__((address_space(3))) void* gdst_t;

DEV void gld16(const void* g, void* l){ __builtin_amdgcn_global_load_lds((gsrc_t)g,(gdst_t)l,16,0,0); }
DEV void gld4 (const void* g, void* l){ __builtin_amdgcn_global_load_lds((gsrc_t)g,(gdst_t)l, 4,0,0); }

DEV unsigned short f2bf(float f){
  union { float f; unsigned int u; } x; x.f = f;
  unsigned int u = x.u;
  return (unsigned short)((u + 0x7fffu + ((u >> 16) & 1u)) >> 16);
}
DEV unsigned long long pack4bf(float a, float b, float c, float d){
  return (unsigned long long)f2bf(a)
       | ((unsigned long long)f2bf(b) << 16)
       | ((unsigned long long)f2bf(c) << 32)
       | ((unsigned long long)f2bf(d) << 48);
}
DEV float gelu_t(float x){
  float u = 0.7978845608028654f * (x + 0.044715f * x * x * x);
  return 0.5f * x * (1.0f + tanhf(u));
}
DEV float sigmoidf_(float x){ return 1.0f / (1.0f + expf(-x)); }

DEV void BAR_TOP(){ __builtin_amdgcn_s_barrier(); asm volatile("" ::: "memory"); }
DEV void BAR_END(){
  __builtin_amdgcn_sched_barrier(0);
  asm volatile("s_waitcnt lgkmcnt(0)" ::: "memory");
  __builtin_amdgcn_s_barrier();
  asm volatile("" ::: "memory");
}

// ---------------- dec_w transpose: [512][32000] f32 -> [32000][512] bf16
__global__ __launch_bounds__(256) void kTdec(const float* __restrict__ W,
                                             unsigned short* __restrict__ out){
  __shared__ float t[64][65];
  int n0 = blockIdx.x * 64, k0 = blockIdx.y * 64;
  int tid = threadIdx.x;
  #pragma unroll
  for (int i = 0; i < 16; i++){
    int idx = i * 256 + tid; int r = idx >> 6, c = idx & 63;
    t[r][c] = W[(size_t)(k0 + r) * 32000 + n0 + c];
  }
  __syncthreads();
  #pragma unroll
  for (int i = 0; i < 16; i++){
    int idx = i * 256 + tid; int r = idx >> 6, c = idx & 63;
    out[(size_t)(n0 + r) * 512 + k0 + c] = f2bf(t[c][r]);
  }
}

// ---------------- batched 512x512 transposes: 3x bf16-out, 2x f32-out
__global__ __launch_bounds__(256) void kT5(const float* __restrict__ s0, const float* __restrict__ s1,
                                           const float* __restrict__ s2, const float* __restrict__ s3,
                                           const float* __restrict__ s4,
                                           unsigned short* __restrict__ d0, unsigned short* __restrict__ d1,
                                           unsigned short* __restrict__ d2,
                                           float* __restrict__ d3, float* __restrict__ d4){
  __shared__ float t[64][65];
  int z = blockIdx.z;
  const float* W = (z == 0) ? s0 : (z == 1) ? s1 : (z == 2) ? s2 : (z == 3) ? s3 : s4;
  int n0 = blockIdx.x * 64, k0 = blockIdx.y * 64;
  int tid = threadIdx.x;
  #pragma unroll
  for (int i = 0; i < 16; i++){
    int idx = i * 256 + tid; int r = idx >> 6, c = idx & 63;
    t[r][c] = W[(size_t)(k0 + r) * 512 + n0 + c];
  }
  __syncthreads();
  #pragma unroll
  for (int i = 0; i < 16; i++){
    int idx = i * 256 + tid; int r = idx >> 6, c = idx & 63;
    float v = t[c][r];
    if (z < 3){
      unsigned short* D = (z == 0) ? d0 : (z == 1) ? d1 : d2;
      D[(size_t)(n0 + r) * 512 + k0 + c] = f2bf(v);
    } else {
      float* D = (z == 3) ? d3 : d4;
      D[(size_t)(n0 + r) * 512 + k0 + c] = v;
    }
  }
}

// ---------------- embedding gather -> bf16 rows; block 0 zeroes ctl counters
__global__ __launch_bounds__(128) void kGather(const int* __restrict__ ids,
                                               const float* __restrict__ embed,
                                               unsigned short* __restrict__ E,
                                               unsigned int* __restrict__ cnt){
  int row = blockIdx.x, tid = threadIdx.x;
  if (row == 0 && tid < 16) cnt[tid] = 0u;
  int id = ids[row];
  float4 v = ((const float4*)(embed + (size_t)id * 512))[tid];
  *(unsigned long long*)(E + (size_t)row * 512 + tid * 4) = pack4bf(v.x, v.y, v.z, v.w);
}

// ---------------- controller tail: executed by the last block of each batch
DEV void ctl_tail(int b, int tid, unsigned int* cnt, int slot,
                  const float* part,
                  const float* idx_wT, const float* idx_b,
                  const float* mu_w, const float* mu_b,
                  const float* sig_w, const float* sig_b,
                  const float* pool_table,
                  const float* w1bT, const float* int_b1,
                  float* r2out, float* outIdx, int nextloop,
                  float* cpool, float* cred, float* cred2, float* cev, float* csc,
                  unsigned int* sLast){
  __syncthreads();                       // all part/state stores issued & drained
  __threadfence();                       // release: flush to device scope
  if (tid == 0) *sLast = atomicAdd(&cnt[slot * 4 + b], 1u);
  __syncthreads();
  if (*sLast != 31u) return;             // uniform per block
  __threadfence();                       // acquire: invalidate caches
  float s = 0.f;
  #pragma unroll 8
  for (int c2 = 0; c2 < 32; c2++) s += part[(size_t)(b * 32 + c2) * 512 + tid];
  cpool[tid] = s * (1.0f / 1024.0f);
  __syncthreads();
  float a = idx_b[tid];
  const float4* wr = (const float4*)(idx_wT + (size_t)tid * 512);
  const float4* p4 = (const float4*)cpool;
  #pragma unroll 8
  for (int i = 0; i < 128; i++){
    float4 wv = wr[i], pv = p4[i];
    a += wv.x * pv.x + wv.y * pv.y + wv.z * pv.z + wv.w * pv.w;
  }
  float hv = gelu_t(a);
  cred[tid] = hv * mu_w[tid];
  cred2[tid] = hv * sig_w[tid];
  __syncthreads();
  for (int off = 256; off > 0; off >>= 1){
    if (tid < off){ cred[tid] += cred[tid + off]; cred2[tid] += cred2[tid + off]; }
    __syncthreads();
  }
  if (tid == 0){
    float mu = sigmoidf_(cred[0] + mu_b[0]);
    float sg = log1pf(expf(cred2[0] + sig_b[0])) + 1e-4f;
    float center = mu * 250000.0f;
    int stt = (int)floorf(center - 32.0f);
    stt = stt < 0 ? 0 : (stt > 250000 - 64 ? 250000 - 64 : stt);
    csc[0] = mu; csc[1] = sg; csc[2] = (float)stt;
    outIdx[b * 4 + nextloop] = (float)stt;
  }
  __syncthreads();
  if (tid < 64){
    float pos = (csc[2] + (float)tid) * (1.0f / 250000.0f);
    float z = (pos - csc[0]) / csc[1];
    cev[tid] = expf(-0.5f * z * z);
  }
  __syncthreads();
  if (tid == 0){
    float ws = 0.f;
    for (int j = 0; j < 64; j++) ws += cev[j];
    csc[3] = ws;
  }
  __syncthreads();
  int stt = (int)csc[2];
  float r = 0.f;
  #pragma unroll 8
  for (int j = 0; j < 64; j++) r += cev[j] * pool_table[(size_t)(stt + j) * 512 + tid];
  r /= csc[3];
  __syncthreads();
  cpool[tid] = r;
  __syncthreads();
  float a2 = int_b1[tid];
  const float4* w2r = (const float4*)(w1bT + (size_t)tid * 512);
  #pragma unroll 8
  for (int i = 0; i < 128; i++){
    float4 wv = w2r[i], pv = p4[i];
    a2 += wv.x * pv.x + wv.y * pv.y + wv.z * pv.z + wv.w * pv.w;
  }
  r2out[(size_t)b * 512 + tid] = a2;
}

// ---------------- encode: 32x512 GEMM + gelu + LN + halt init + part + ctl(slot0)
__global__ __launch_bounds__(512) void kEnc(
    const unsigned short* __restrict__ A, const unsigned short* __restrict__ BT,
    const float* __restrict__ bias, const float* __restrict__ lns, const float* __restrict__ lnb,
    float* __restrict__ st, unsigned short* __restrict__ stb,
    float* __restrict__ part, float* __restrict__ halt_p, float* __restrict__ halted,
    unsigned int* __restrict__ cnt,
    const float* __restrict__ idx_wT, const float* __restrict__ idx_b,
    const float* __restrict__ mu_w, const float* __restrict__ mu_b,
    const float* __restrict__ sig_w, const float* __restrict__ sig_b,
    const float* __restrict__ pool_table,
    const float* __restrict__ w1bT, const float* __restrict__ int_b1,
    float* __restrict__ r2out, float* __restrict__ outIdx){
  __shared__ alignas(16) unsigned short lA[2][32 * 32];
  __shared__ alignas(16) unsigned short lB[2][512 * 32];
  __shared__ float pS[8][32], pQ[8][32];
  __shared__ float sMean[32], sRs[32];
  __shared__ unsigned int sLast;
  const int tid = threadIdx.x, w = tid >> 6, lane = tid & 63;
  const int q = lane >> 4, c = lane & 15, lk8 = q * 8;
  const int r0 = blockIdx.x * 32;
  const int b = blockIdx.x >> 5;
  const int ar = tid >> 4, ak = (tid & 15) * 2;
  const int br = tid >> 2, bk = (tid & 3) * 8;
  f32x4 acc[2][4] = {};

  auto STAGE = [&](int buf, int k0){
    gld4 (A  + (size_t)(r0 + ar) * 512 + k0 + ak, &lA[buf][ar * 32 + ak]);
    #pragma unroll
    for (int i = 0; i < 4; i++)
      gld16(BT + (size_t)(i * 128 + br) * 512 + k0 + bk, &lB[buf][(i * 512 + tid) * 8]);
  };

  STAGE(0, 0);
  #pragma unroll
  for (int t = 0; t < 16; t++){
    if (t < 15){
      STAGE((t + 1) & 1, (t + 1) * 32);
      asm volatile("s_waitcnt vmcnt(5)" ::: "memory");
    } else {
      asm volatile("s_waitcnt vmcnt(0)" ::: "memory");
    }
    BAR_TOP();
    bf16x8 af[2], bfv[4];
    #pragma unroll
    for (int m = 0; m < 2; m++) af[m]  = *(const bf16x8*)&lA[t & 1][(m * 16 + c) * 32 + lk8];
    #pragma unroll
    for (int n = 0; n < 4; n++) bfv[n] = *(const bf16x8*)&lB[t & 1][(w * 64 + n * 16 + c) * 32 + lk8];
    #pragma unroll
    for (int m = 0; m < 2; m++)
      #pragma unroll
      for (int n = 0; n < 4; n++)
        acc[m][n] = __builtin_amdgcn_mfma_f32_16x16x32_bf16(af[m], bfv[n], acc[m][n], 0, 0, 0);
    BAR_END();
  }

  // bias + gelu
  #pragma unroll
  for (int n = 0; n < 4; n++){
    float bcol = bias[w * 64 + n * 16 + c];
    #pragma unroll
    for (int m = 0; m < 2; m++)
      #pragma unroll
      for (int r = 0; r < 4; r++)
        acc[m][n][r] = gelu_t(acc[m][n][r] + bcol);
  }
  // LN stats
  float rS[2][4], rQ[2][4];
  #pragma unroll
  for (int m = 0; m < 2; m++)
    #pragma unroll
    for (int r = 0; r < 4; r++){
      float s = 0.f, s2 = 0.f;
      #pragma unroll
      for (int n = 0; n < 4; n++){ float v = acc[m][n][r]; s += v; s2 += v * v; }
      rS[m][r] = s; rQ[m][r] = s2;
    }
  #pragma unroll
  for (int mask = 1; mask < 16; mask <<= 1)
    #pragma unroll
    for (int m = 0; m < 2; m++)
      #pragma unroll
      for (int r = 0; r < 4; r++){
        rS[m][r] += __shfl_xor(rS[m][r], mask);
        rQ[m][r] += __shfl_xor(rQ[m][r], mask);
      }
  if (c == 0)
    #pragma unroll
    for (int m = 0; m < 2; m++)
      #pragma unroll
      for (int r = 0; r < 4; r++){
        pS[w][m * 16 + q * 4 + r] = rS[m][r];
        pQ[w][m * 16 + q * 4 + r] = rQ[m][r];
      }
  __syncthreads();
  if (tid < 32){
    float s = 0.f, s2 = 0.f;
    #pragma unroll
    for (int v = 0; v < 8; v++){ s += pS[v][tid]; s2 += pQ[v][tid]; }
    float mean = s * (1.f / 512.f);
    float var  = s2 * (1.f / 512.f) - mean * mean;
    sMean[tid] = mean; sRs[tid] = rsqrtf(var + 1e-5f);
    halt_p[r0 + tid] = 0.f; halted[r0 + tid] = 0.f;
  }
  __syncthreads();
  float lnsv[4], lnbv[4];
  #pragma unroll
  for (int n = 0; n < 4; n++){ lnsv[n] = lns[w * 64 + n * 16 + c]; lnbv[n] = lnb[w * 64 + n * 16 + c]; }
  #pragma unroll
  for (int m = 0; m < 2; m++)
    #pragma unroll
    for (int r = 0; r < 4; r++){
      int row = m * 16 + q * 4 + r;
      float mu = sMean[row], rs = sRs[row];
      #pragma unroll
      for (int n = 0; n < 4; n++)
        acc[m][n][r] = (acc[m][n][r] - mu) * rs * lnsv[n] + lnbv[n];
    }
  // write state + part
  #pragma unroll
  for (int m = 0; m < 2; m++)
    #pragma unroll
    for (int r = 0; r < 4; r++){
      int row = r0 + m * 16 + q * 4 + r;
      #pragma unroll
      for (int n = 0; n < 4; n++){
        int col = w * 64 + n * 16 + c;
        float v = acc[m][n][r];
        st [(size_t)row * 512 + col] = v;
        stb[(size_t)row * 512 + col] = f2bf(v);
      }
    }
  #pragma unroll
  for (int n = 0; n < 4; n++){
    float s = 0.f;
    #pragma unroll
    for (int m = 0; m < 2; m++)
      #pragma unroll
      for (int r = 0; r < 4; r++) s += acc[m][n][r];
    s += __shfl_xor(s, 16);
    s += __shfl_xor(s, 32);
    if (q == 0) part[(size_t)blockIdx.x * 512 + w * 64 + n * 16 + c] = s;
  }
  // fused controller for loop 0
  float* cs = (float*)&lB[0][0];
  ctl_tail(b, tid, cnt, 0, part, idx_wT, idx_b, mu_w, mu_b, sig_w, sig_b,
           pool_table, w1bT, int_b1, r2out, outIdx, 0,
           cs, cs + 512, cs + 1024, cs + 1536, cs + 1600, &sLast);
}

// ---------------- fused ACT loop: GEMM1(swapped->G in LDS) + GEMM2 + LN + ACT + part + ctl
__global__ __launch_bounds__(512) void kLoop(
    const unsigned short* __restrict__ A,      // state_b
    const unsigned short* __restrict__ W1T, const unsigned short* __restrict__ W2T,
    const float* __restrict__ r2in, const float* __restrict__ b2,
    const float* __restrict__ lns, const float* __restrict__ lnb,
    const float* __restrict__ hw, const float* __restrict__ hb,
    float* __restrict__ st, unsigned short* __restrict__ stb,
    float* __restrict__ part, float* __restrict__ halt_p, float* __restrict__ halted,
    unsigned int* __restrict__ cnt, int slot, int doCtl,
    const float* __restrict__ idx_wT, const float* __restrict__ idx_b,
    const float* __restrict__ mu_w, const float* __restrict__ mu_b,
    const float* __restrict__ sig_w, const float* __restrict__ sig_b,
    const float* __restrict__ pool_table,
    const float* __restrict__ w1bT, const float* __restrict__ int_b1,
    float* __restrict__ r2out, float* __restrict__ outIdx, int nextloop){
  __shared__ alignas(16) unsigned short lA[2][32 * 32];
  __shared__ alignas(16) unsigned short lB[2][512 * 32];
  __shared__ alignas(16) unsigned short G[32 * 512];        // swizzled
  __shared__ float pS[8][32], pQ[8][32], pH[8][32];
  __shared__ float sMean[32], sRs[32], sFac[32];
  __shared__ unsigned int sLast;
  const int tid = threadIdx.x, w = tid >> 6, lane = tid & 63;
  const int q = lane >> 4, c = lane & 15, lk8 = q * 8;
  const int r0 = blockIdx.x * 32;
  const int b = blockIdx.x >> 5;
  const int ar = tid >> 4, ak = (tid & 15) * 2;
  const int br = tid >> 2, bk = (tid & 3) * 8;

  // rowbias (r2 incl. int_b1) for this wave's G-cols; drain before pipeline
  float4 rbv[4];
  #pragma unroll
  for (int m2 = 0; m2 < 4; m2++)
    rbv[m2] = *(const float4*)(r2in + b * 512 + w * 64 + m2 * 16 + q * 4);
  asm volatile("s_waitcnt vmcnt(0)" ::: "memory");

  auto STG = [&](int buf, const unsigned short* W, int k0, bool withA){
    if (withA) gld4(A + (size_t)(r0 + ar) * 512 + k0 + ak, &lA[buf][ar * 32 + ak]);
    #pragma unroll
    for (int i = 0; i < 4; i++)
      gld16(W + (size_t)(i * 128 + br) * 512 + k0 + bk, &lB[buf][(i * 512 + tid) * 8]);
  };

  // -------- phase 1: G^T = W1T x state  (D rows = G cols)
  f32x4 acc1[4][2] = {};
  STG(0, W1T, 0, true);
  #pragma unroll
  for (int t = 0; t < 16; t++){
    if (t < 15){
      STG((t + 1) & 1, W1T, (t + 1) * 32, true);
      asm volatile("s_waitcnt vmcnt(5)" ::: "memory");
    } else {
      STG(0, W2T, 0, false);                       // prefetch W2T tile 0 into buf0
      asm volatile("s_waitcnt vmcnt(4)" ::: "memory");
    }
    BAR_TOP();
    bf16x8 afw[4], bfs[2];
    #pragma unroll
    for (int m2 = 0; m2 < 4; m2++) afw[m2] = *(const bf16x8*)&lB[t & 1][(w * 64 + m2 * 16 + c) * 32 + lk8];
    #pragma unroll
    for (int n2 = 0; n2 < 2; n2++) bfs[n2] = *(const bf16x8*)&lA[t & 1][(n2 * 16 + c) * 32 + lk8];
    #pragma unroll
    for (int m2 = 0; m2 < 4; m2++)
      #pragma unroll
      for (int n2 = 0; n2 < 2; n2++)
        acc1[m2][n2] = __builtin_amdgcn_mfma_f32_16x16x32_bf16(afw[m2], bfs[n2], acc1[m2][n2], 0, 0, 0);
    BAR_END();
  }

  // G epilogue: gelu(G + rowbias) -> swizzled LDS (row=G-row, 4 consecutive cols/lane)
  #pragma unroll
  for (int m2 = 0; m2 < 4; m2++)
    #pragma unroll
    for (int n2 = 0; n2 < 2; n2++){
      float v0 = gelu_t(acc1[m2][n2][0] + rbv[m2].x);
      float v1 = gelu_t(acc1[m2][n2][1] + rbv[m2].y);
      float v2 = gelu_t(acc1[m2][n2][2] + rbv[m2].z);
      float v3 = gelu_t(acc1[m2][n2][3] + rbv[m2].w);
      int row = n2 * 16 + c;
      int byo = row * 1024 + (w * 128 + m2 * 32 + q * 8);
      byo ^= (c & 7) << 4;
      *(unsigned long long*)((char*)G + byo) = pack4bf(v0, v1, v2, v3);
    }
  BAR_END();   // G visible to all waves

  // -------- phase 2: Y = G x W2T
  f32x4 acc[2][4] = {};
  #pragma unroll
  for (int t = 0; t < 16; t++){
    if (t < 15){
      STG((t + 1) & 1, W2T, (t + 1) * 32, false);
      asm volatile("s_waitcnt vmcnt(4)" ::: "memory");
    } else {
      asm volatile("s_waitcnt vmcnt(0)" ::: "memory");
    }
    BAR_TOP();
    bf16x8 afg[2], bfw[4];
    #pragma unroll
    for (int m = 0; m < 2; m++){
      int byo = (m * 16 + c) * 1024 + t * 64 + q * 16;
      byo ^= (c & 7) << 4;
      afg[m] = *(const bf16x8*)((const char*)G + byo);
    }
    #pragma unroll
    for (int n = 0; n < 4; n++) bfw[n] = *(const bf16x8*)&lB[t & 1][(w * 64 + n * 16 + c) * 32 + lk8];
    #pragma unroll
    for (int m = 0; m < 2; m++)
      #pragma unroll
      for (int n = 0; n < 4; n++)
        acc[m][n] = __builtin_amdgcn_mfma_f32_16x16x32_bf16(afg[m], bfw[n], acc[m][n], 0, 0, 0);
    BAR_END();
  }

  // -------- epilogue: +b2, LN, ACT halting, state update, part
  #pragma unroll
  for (int n = 0; n < 4; n++){
    float bcol = b2[w * 64 + n * 16 + c];
    #pragma unroll
    for (int m = 0; m < 2; m++)
      #pragma unroll
      for (int r = 0; r < 4; r++) acc[m][n][r] += bcol;
  }
  float rS[2][4], rQ[2][4];
  #pragma unroll
  for (int m = 0; m < 2; m++)
    #pragma unroll
    for (int r = 0; r < 4; r++){
      float s = 0.f, s2 = 0.f;
      #pragma unroll
      for (int n = 0; n < 4; n++){ float v = acc[m][n][r]; s += v; s2 += v * v; }
      rS[m][r] = s; rQ[m][r] = s2;
    }
  #pragma unroll
  for (int mask = 1; mask < 16; mask <<= 1)
    #pragma unroll
    for (int m = 0; m < 2; m++)
      #pragma unroll
      for (int r = 0; r < 4; r++){
        rS[m][r] += __shfl_xor(rS[m][r], mask);
        rQ[m][r] += __shfl_xor(rQ[m][r], mask);
      }
  if (c == 0)
    #pragma unroll
    for (int m = 0; m < 2; m++)
      #pragma unroll
      for (int r = 0; r < 4; r++){
        pS[w][m * 16 + q * 4 + r] = rS[m][r];
        pQ[w][m * 16 + q * 4 + r] = rQ[m][r];
      }
  __syncthreads();
  if (tid < 32){
    float s = 0.f, s2 = 0.f;
    #pragma unroll
    for (int v = 0; v < 8; v++){ s += pS[v][tid]; s2 += pQ[v][tid]; }
    float mean = s * (1.f / 512.f);
    float var  = s2 * (1.f / 512.f) - mean * mean;
    sMean[tid] = mean; sRs[tid] = rsqrtf(var + 1e-5f);
  }
  __syncthreads();
  float lnsv[4], lnbv[4], hwv[4];
  #pragma unroll
  for (int n = 0; n < 4; n++){
    lnsv[n] = lns[w * 64 + n * 16 + c];
    lnbv[n] = lnb[w * 64 + n * 16 + c];
    hwv[n]  = hw [w * 64 + n * 16 + c];
  }
  #pragma unroll
  for (int m = 0; m < 2; m++)
    #pragma unroll
    for (int r = 0; r < 4; r++){
      int row = m * 16 + q * 4 + r;
      float mu = sMean[row], rs = sRs[row];
      #pragma unroll
      for (int n = 0; n < 4; n++)
        acc[m][n][r] = (acc[m][n][r] - mu) * rs * lnsv[n] + lnbv[n];
    }
  float sold[2][4][4];
  #pragma unroll
  for (int m = 0; m < 2; m++)
    #pragma unroll
    for (int r = 0; r < 4; r++){
      int row = m * 16 + q * 4 + r;
      #pragma unroll
      for (int n = 0; n < 4; n++)
        sold[m][n][r] = st[(size_t)(r0 + row) * 512 + w * 64 + n * 16 + c];
    }
  float rH[2][4];
  #pragma unroll
  for (int m = 0; m < 2; m++)
    #pragma unroll
    for (int r = 0; r < 4; r++){
      float d = 0.f;
      #pragma unroll
      for (int n = 0; n < 4; n++) d += (sold[m][n][r] + acc[m][n][r]) * hwv[n];
      rH[m][r] = d;
    }
  #pragma unroll
  for (int mask = 1; mask < 16; mask <<= 1)
    #pragma unroll
    for (int m = 0; m < 2; m++)
      #pragma unroll
      for (int r = 0; r < 4; r++) rH[m][r] += __shfl_xor(rH[m][r], mask);
  if (c == 0)
    #pragma unroll
    for (int m = 0; m < 2; m++)
      #pragma unroll
      for (int r = 0; r < 4; r++) pH[w][m * 16 + q * 4 + r] = rH[m][r];
  __syncthreads();
  if (tid < 32){
    float d = 0.f;
    #pragma unroll
    for (int v = 0; v < 8; v++) d += pH[v][tid];
    float hd = halted[r0 + tid];
    float p  = sigmoidf_(d + hb[0]);
    float hp = halt_p[r0 + tid] + p * (1.f - hd);
    halt_p[r0 + tid] = hp;
    halted[r0 + tid] = (hp > 0.99f) ? 1.f : 0.f;
    sFac[tid] = 1.f - hd;
  }
  __syncthreads();
  #pragma unroll
  for (int m = 0; m < 2; m++)
    #pragma unroll
    for (int r = 0; r < 4; r++){
      int row = m * 16 + q * 4 + r;
      float f = sFac[row];
      #pragma unroll
      for (int n = 0; n < 4; n++)
        acc[m][n][r] = sold[m][n][r] + f * acc[m][n][r];
    }
  #pragma unroll
  for (int m = 0; m < 2; m++)
    #pragma unroll
    for (int r = 0; r < 4; r++){
      int row = r0 + m * 16 + q * 4 + r;
      #pragma unroll
      for (int n = 0; n < 4; n++){
        int col = w * 64 + n * 16 + c;
        float v = acc[m][n][r];
        st [(size_t)row * 512 + col] = v;
        stb[(size_t)row * 512 + col] = f2bf(v);
      }
    }
  #pragma unroll
  for (int n = 0; n < 4; n++){
    float s = 0.f;
    #pragma unroll
    for (int m = 0; m < 2; m++)
      #pragma unroll
      for (int r = 0; r < 4; r++) s += acc[m][n][r];
    s += __shfl_xor(s, 16);
    s += __shfl_xor(s, 32);
    if (q == 0) part[(size_t)blockIdx.x * 512 + w * 64 + n * 16 + c] = s;
  }
  if (doCtl){
    float* cs = (float*)&lB[0][0];
    ctl_tail(b, tid, cnt, slot, part, idx_wT, idx_b, mu_w, mu_b, sig_w, sig_b,
             pool_table, w1bT, int_b1, r2out, outIdx, nextloop,
             cs, cs + 512, cs + 1024, cs + 1536, cs + 1600, &sLast);
  }
}

// ---------------- decoder GEMM: 128x128 tile, m97 structure + XCD swizzle, fp32 out + bias
__global__ __launch_bounds__(256) void kGemmDec(const unsigned short* __restrict__ A,
                                                const unsigned short* __restrict__ BT,
                                                const float* __restrict__ bias,
                                                float* __restrict__ C){
  __shared__ alignas(16) unsigned short lA[128 * 32];
  __shared__ alignas(16) unsigned short lB[128 * 32];
  const int tid = threadIdx.x;
  const int w = tid >> 6, lane = tid & 63;
  int flat = blockIdx.y * gridDim.x + blockIdx.x;
  {
    int tot = gridDim.x * gridDim.y;           // 8000, divisible by 8
    int xcd = flat & 7, pos = flat >> 3;
    flat = xcd * (tot >> 3) + pos;
  }
  const int n0 = (flat % gridDim.x) * 128;
  const int m0 = (flat / gridDim.x) * 128;
  const int wm = w >> 1, wn = w & 1;
  const int lr = lane & 15;
  const int lk = (lane >> 4) * 8;
  f32x4 acc[4][4] = {};

  for (int k0 = 0; k0 < 512; k0 += 32){
    __syncthreads();
    #pragma unroll
    for (int cc = 0; cc < 2; cc++){
      int row = w * 32 + cc * 16 + (lane >> 2);
      int kk  = k0 + (lane & 3) * 8;
      gld16(A  + (size_t)(m0 + row) * 512 + kk, &lA[(w * 32 + cc * 16) * 32]);
      gld16(BT + (size_t)(n0 + row) * 512 + kk, &lB[(w * 32 + cc * 16) * 32]);
    }
    __syncthreads();
    bf16x8 af[4], bfr[4];
    #pragma unroll
    for (int m = 0; m < 4; m++) af[m]  = *(const bf16x8*)&lA[(wm * 64 + m * 16 + lr) * 32 + lk];
    #pragma unroll
    for (int n = 0; n < 4; n++) bfr[n] = *(const bf16x8*)&lB[(wn * 64 + n * 16 + lr) * 32 + lk];
    #pragma unroll
    for (int m = 0; m < 4; m++)
      #pragma unroll
      for (int n = 0; n < 4; n++)
        acc[m][n] = __builtin_amdgcn_mfma_f32_16x16x32_bf16(af[m], bfr[n], acc[m][n], 0, 0, 0);
  }

  #pragma unroll
  for (int m = 0; m < 4; m++){
    int rbase = m0 + wm * 64 + m * 16 + (lane >> 4) * 4;
    #pragma unroll
    for (int n = 0; n < 4; n++){
      int col = n0 + wn * 64 + n * 16 + (lane & 15);
      float bcol = bias[col];
      #pragma unroll
      for (int r = 0; r < 4; r++)
        C[(size_t)(rbase + r) * 32000 + col] = acc[m][n][r] + bcol;
    }
  }
}

extern "C" void kernel_launch(void* const* d_in, const int* in_sizes, int n_in,
                              void* d_out, int out_size, void* d_ws, size_t ws_size,
                              hipStream_t stream){
  (void)in_sizes; (void)n_in; (void)out_size; (void)ws_size;
  const int*   ids    = (const int*)  d_in[0];
  const float* embed  = (const float*)d_in[1];
  const float* enc_w  = (const float*)d_in[2];
  const float* enc_b  = (const float*)d_in[3];
  const float* ln_es  = (const float*)d_in[4];
  const float* ln_eb  = (const float*)d_in[5];
  const float* idx_w  = (const float*)d_in[6];
  const float* idx_b  = (const float*)d_in[7];
  const float* mu_w   = (const float*)d_in[8];
  const float* mu_b   = (const float*)d_in[9];
  const float* sig_w  = (const float*)d_in[10];
  const float* sig_b  = (const float*)d_in[11];
  const float* pool_t = (const float*)d_in[12];
  const float* int_w1 = (const float*)d_in[13];
  const float* int_b1 = (const float*)d_in[14];
  const float* int_w2 = (const float*)d_in[15];
  const float* int_b2 = (const float*)d_in[16];
  const float* ln_s   = (const float*)d_in[17];
  const float* ln_b   = (const float*)d_in[18];
  const float* halt_w = (const float*)d_in[19];
  const float* halt_b = (const float*)d_in[20];
  const float* dec_w  = (const float*)d_in[21];
  const float* dec_b  = (const float*)d_in[22];

  char* ws = (char*)d_ws;
  size_t off = 0;
  auto alloc = [&](size_t bytes)->char*{
    char* p = ws + off; off += (bytes + 255) & ~(size_t)255; return p;
  };
  unsigned short* dec_wT  = (unsigned short*)alloc(32000ull * 512 * 2);
  unsigned short* enc_wT  = (unsigned short*)alloc(512ull * 512 * 2);
  unsigned short* w1T     = (unsigned short*)alloc(512ull * 512 * 2);
  unsigned short* w2T     = (unsigned short*)alloc(512ull * 512 * 2);
  float*          idx_wT  = (float*)alloc(512ull * 512 * 4);
  float*          w1bT    = (float*)alloc(512ull * 512 * 4);
  unsigned short* bufB    = (unsigned short*)alloc(4096ull * 512 * 2);
  float*          state   = (float*)alloc(4096ull * 512 * 4);
  unsigned short* state_b = (unsigned short*)alloc(4096ull * 512 * 2);
  float*          part    = (float*)alloc(128ull * 512 * 4);
  float*          r2b     = (float*)alloc(2ull * 4 * 512 * 4);
  float*          halt_p  = (float*)alloc(4096 * 4);
  float*          halted  = (float*)alloc(4096 * 4);
  unsigned int*   cnt     = (unsigned int*)alloc(16 * 4);
  float*          outF    = (float*)d_out;

  // weight prep
  hipLaunchKernelGGL(kTdec, dim3(500, 8), dim3(256), 0, stream, dec_w, dec_wT);
  hipLaunchKernelGGL(kT5, dim3(8, 8, 5), dim3(256), 0, stream,
                     enc_w, int_w1, int_w2, idx_w, int_w1 + 512 * 512,
                     enc_wT, w1T, w2T, idx_wT, w1bT);

  // encode (+ctl slot0)
  hipLaunchKernelGGL(kGather, dim3(4096), dim3(128), 0, stream, ids, embed, bufB, cnt);
  hipLaunchKernelGGL(kEnc, dim3(128), dim3(512), 0, stream,
                     bufB, enc_wT, enc_b, ln_es, ln_eb,
                     state, state_b, part, halt_p, halted, cnt,
                     idx_wT, idx_b, mu_w, mu_b, sig_w, sig_b, pool_t,
                     w1bT, int_b1, r2b, outF + 131072000);

  // 4 fused ACT loops
  for (int l = 0; l < 4; l++){
    hipLaunchKernelGGL(kLoop, dim3(128), dim3(512), 0, stream,
                       state_b, w1T, w2T,
                       r2b + (l & 1) * 2048, int_b2, ln_s, ln_b, halt_w, halt_b,
                       state, state_b, part, halt_p, halted,
                       cnt, l + 1, (l < 3) ? 1 : 0,
                       idx_wT, idx_b, mu_w, mu_b, sig_w, sig_b, pool_t,
                       w1bT, int_b1, r2b + ((l + 1) & 1) * 2048,
                       outF + 131072000, l + 1);
  }

  // decoder
  hipLaunchKernelGGL(kGemmDec, dim3(250, 32), dim3(256), 0, stream,
                     state_b, dec_wT, dec_b, (float*)d_out);
}